// Round 8
// baseline (431.484 us; speedup 1.0000x reference)
//
#include <hip/hip_runtime.h>

#define B_TOT   4096
#define T_STEPS 512
#define IN_F    5
#define D_FC    32
#define D_H     64
#define MB      4       // batches per block: batch b -> M-row 4b (1 valid row/quad)
#define NROW    16      // MFMA M-tile rows staged in LDS
#define ROWPAD  104     // f16 elems per row (96 + 8 pad; rows stay 16B-aligned)

typedef _Float16 h8 __attribute__((ext_vector_type(8)));
typedef float    f4 __attribute__((ext_vector_type(4)));

#define LOG2E    1.4426950408889634f
#define TWOLOG2E 2.8853900817779268f

__device__ __forceinline__ float fexp2(float x) { return __builtin_amdgcn_exp2f(x); }
__device__ __forceinline__ float frcp(float x)  { return __builtin_amdgcn_rcpf(x); }

// 128-thread block (2 waves), 4 batches, grid 1024 -> 4 independent barrier
// domains per CU, 2 waves/SIMD. Wave w owns gate columns j in w*32..w*32+31.
__global__ __launch_bounds__(128, 2) void lstm_mfma(
    const float* __restrict__ x,
    const float* __restrict__ W0,
    const float* __restrict__ b0,
    const float* __restrict__ W_ih,
    const float* __restrict__ W_hh,
    const float* __restrict__ b_ih,
    const float* __restrict__ b_hh,
    const float* __restrict__ Wo,
    const float* __restrict__ bo,
    float* __restrict__ out)
{
    // H[buf][row][k]: k 0..31 = h0(t) (fc0 out), 32..95 = h(t-1), f16
    __shared__ _Float16 H[2][NROW][ROWPAD];

    const int tid  = threadIdx.x;
    const int lane = tid & 63;
    const int w    = tid >> 6;      // wave id (0,1): owns j in [w*32, w*32+32)
    const int col  = lane & 15;
    const int quad = lane >> 4;     // = batch index (row 4*quad, acc reg 0)
    const int bblk = blockIdx.x * MB;

    // ---- resident B-fragments: 8 N-tiles (4 gates x 2 j-groups) x 3 K-chunks ----
    // tile (q,jg): columns n = q*64 + w*32 + jg*16 + col
    h8 Bf[4][2][3];
    #pragma unroll
    for (int q = 0; q < 4; ++q) {
        #pragma unroll
        for (int jg = 0; jg < 2; ++jg) {
            const int n = q * 64 + w * 32 + jg * 16 + col;
            #pragma unroll
            for (int c = 0; c < 3; ++c) {
                h8 f;
                #pragma unroll
                for (int jj = 0; jj < 8; ++jj) {
                    const int k = c * 32 + quad * 8 + jj;
                    const float wv = (k < D_FC) ? W_ih[n * D_FC + k]
                                                : W_hh[n * D_H + (k - D_FC)];
                    f[jj] = (_Float16)wv;
                }
                Bf[q][jg][c] = f;
            }
        }
    }
    // biases pre-scaled for exp2-arg folding: sig -> -LOG2E*b, tanh -> TWOLOG2E*b
    float bsc[4][2];
    #pragma unroll
    for (int q = 0; q < 4; ++q)
        #pragma unroll
        for (int jg = 0; jg < 2; ++jg) {
            const int n = q * 64 + w * 32 + jg * 16 + col;
            const float bf = b_ih[n] + b_hh[n];
            bsc[q][jg] = (q == 2) ? TWOLOG2E * bf : -LOG2E * bf;
        }

    // ---- fc0: thread -> (batch fb, column fc); 128 threads = 4 x 32 exactly ----
    const int fb = tid >> 5;        // 0..3
    const int fc = tid & 31;        // 0..31
    float w0c[IN_F];
    #pragma unroll
    for (int i = 0; i < IN_F; ++i) w0c[i] = W0[fc * IN_F + i];
    const float b0s = b0[fc];

    const float* xb = x + (size_t)(bblk + fb) * T_STEPS * IN_F;

    // ---- zero both buffers (garbage rows must stay 0), then seed h0(0) ----
    {
        unsigned* p = (unsigned*)&H[0][0][0];
        #pragma unroll
        for (int i = 0; i < 13; ++i)            // 2*16*104/2 = 1664 dwords
            p[tid + 128 * i] = 0u;
    }
    __syncthreads();
    {
        float a = b0s;
        #pragma unroll
        for (int i = 0; i < IN_F; ++i) a = fmaf(w0c[i], xb[i], a);
        H[0][4 * fb][fc] = (_Float16)a;
    }
    // prefetch x(t=1)
    float xr[IN_F];
    #pragma unroll
    for (int i = 0; i < IN_F; ++i) xr[i] = xb[IN_F + i];

    // cell state: lane owns (batch quad, j = w*32 + jg*16 + col), jg = 0,1
    float c_st[2] = {0.0f, 0.0f};
    const f4 zero4 = {0.0f, 0.0f, 0.0f, 0.0f};

    __syncthreads();

    for (int t = 0; t < T_STEPS; ++t) {
        const int rp = t & 1, wp = rp ^ 1;

        // A-fragments (b128, 16B aligned)
        const h8 A0 = *(const h8*)&H[rp][col][quad * 8];
        const h8 A1 = *(const h8*)&H[rp][col][32 + quad * 8];
        const h8 A2 = *(const h8*)&H[rp][col][64 + quad * 8];

        f4 acc[4][2];
        #pragma unroll
        for (int q = 0; q < 4; ++q)
            #pragma unroll
            for (int jg = 0; jg < 2; ++jg) {
                f4 a = __builtin_amdgcn_mfma_f32_16x16x32_f16(A0, Bf[q][jg][0], zero4, 0, 0, 0);
                a = __builtin_amdgcn_mfma_f32_16x16x32_f16(A1, Bf[q][jg][1], a, 0, 0, 0);
                a = __builtin_amdgcn_mfma_f32_16x16x32_f16(A2, Bf[q][jg][2], a, 0, 0, 0);
                acc[q][jg] = a;
            }

        // elementwise LSTM: 2 cells per lane (batch=quad is acc reg 0)
        #pragma unroll
        for (int jg = 0; jg < 2; ++jg) {
            const float ii = frcp(1.0f + fexp2(fmaf(-LOG2E,   acc[0][jg][0], bsc[0][jg])));
            const float ff = frcp(1.0f + fexp2(fmaf(-LOG2E,   acc[1][jg][0], bsc[1][jg])));
            const float g_ = fmaf(-2.0f, frcp(1.0f + fexp2(fmaf(TWOLOG2E, acc[2][jg][0], bsc[2][jg]))), 1.0f);
            const float oo = frcp(1.0f + fexp2(fmaf(-LOG2E,   acc[3][jg][0], bsc[3][jg])));
            c_st[jg] = fmaf(ff, c_st[jg], ii * g_);
            const float th = fmaf(-2.0f, frcp(1.0f + fexp2(TWOLOG2E * c_st[jg])), 1.0f);
            H[wp][4 * quad][D_FC + w * 32 + jg * 16 + col] = (_Float16)(oo * th);
        }

        // fc0 for t+1 into write buffer
        {
            float a = b0s;
            #pragma unroll
            for (int i = 0; i < IN_F; ++i) a = fmaf(w0c[i], xr[i], a);
            H[wp][4 * fb][fc] = (_Float16)a;
        }
        // prefetch x(t+2), clamped
        const int tn = (t + 2 < T_STEPS) ? (t + 2) : (T_STEPS - 1);
        #pragma unroll
        for (int i = 0; i < IN_F; ++i) xr[i] = xb[tn * IN_F + i];

        __syncthreads();   // single block-wide barrier per step
    }

    // ---- output head: h_last in buf 0 (T even); batch b at row 4b ----
    if (tid < MB) {
        float a = bo[0];
        #pragma unroll 8
        for (int j = 0; j < D_H; ++j)
            a = fmaf((float)H[0][4 * tid][D_FC + j], Wo[j], a);
        out[bblk + tid] = a;
    }
}

extern "C" void kernel_launch(void* const* d_in, const int* in_sizes, int n_in,
                              void* d_out, int out_size, void* d_ws, size_t ws_size,
                              hipStream_t stream) {
    const float* x    = (const float*)d_in[0];
    const float* W0   = (const float*)d_in[1];
    const float* b0   = (const float*)d_in[2];
    const float* W_ih = (const float*)d_in[3];
    const float* W_hh = (const float*)d_in[4];
    const float* b_ih = (const float*)d_in[5];
    const float* b_hh = (const float*)d_in[6];
    const float* Wo   = (const float*)d_in[7];
    const float* bo   = (const float*)d_in[8];
    float* out = (float*)d_out;

    hipLaunchKernelGGL(lstm_mfma, dim3(B_TOT / MB), dim3(128), 0, stream,
                       x, W0, b0, W_ih, W_hh, b_ih, b_hh, Wo, bo, out);
}

// Round 9
// 407.546 us; speedup vs baseline: 1.0587x; 1.0587x over previous
//
#include <hip/hip_runtime.h>

#define B_TOT   4096
#define T_STEPS 512
#define IN_F    5
#define D_FC    32
#define D_H     64
#define MB      8       // batches per block (mrow pairing: 2 valid rows per quad)
#define NROW    16      // MFMA M-tile rows staged in LDS
#define HOFF    32      // h(t-1) at k 32..95; x at k 0..4 (5..31 stay zero)
#define ROWPAD  104     // f16 per row (13 x 16B, odd -> conflict-free b128)

typedef _Float16 h8 __attribute__((ext_vector_type(8)));
typedef float    f4 __attribute__((ext_vector_type(4)));

#define LOG2E    1.4426950408889634f
#define TWOLOG2E 2.8853900817779268f

__device__ __forceinline__ float fexp2(float x) { return __builtin_amdgcn_exp2f(x); }
__device__ __forceinline__ float frcp(float x)  { return __builtin_amdgcn_rcpf(x); }

// batch b (0..7) -> M-tile row: quads 0..3 each hold 2 valid rows (regs 0,1)
__device__ __forceinline__ int mrow(int b) { return ((b >> 1) << 2) | (b & 1); }

__global__ __launch_bounds__(256, 2) void lstm_mfma(
    const float* __restrict__ x,
    const float* __restrict__ W0,
    const float* __restrict__ b0,
    const float* __restrict__ W_ih,
    const float* __restrict__ W_hh,
    const float* __restrict__ b_ih,
    const float* __restrict__ b_hh,
    const float* __restrict__ Wo,
    const float* __restrict__ bo,
    float* __restrict__ out)
{
    // H[buf][row][k]: k 0..4 = x_t (5..31 zero), 32..95 = h(t-1), f16
    __shared__ _Float16 H[2][NROW][ROWPAD];

    const int tid  = threadIdx.x;
    const int lane = tid & 63;
    const int w    = tid >> 6;      // wave id: owns gate cols j in [w*16, w*16+16)
    const int col  = lane & 15;
    const int quad = lane >> 4;
    const int bblk = blockIdx.x * MB;

    // ---- resident B-fragments ----
    // Bh[q][c]: W_hh chunk c (k = c*32 + quad*8 + jj), n = q*64 + w*16 + col
    // Bx[q]  : fused x-path weights W_xg = W_ih @ W0 (k<5 nonzero, rest 0)
    h8 Bh[4][2], Bx[4];
    float bsc[4];
    #pragma unroll
    for (int q = 0; q < 4; ++q) {
        const int n = q * 64 + w * 16 + col;
        #pragma unroll
        for (int c = 0; c < 2; ++c) {
            h8 f;
            #pragma unroll
            for (int jj = 0; jj < 8; ++jj)
                f[jj] = (_Float16)W_hh[n * D_H + c * 32 + quad * 8 + jj];
            Bh[q][c] = f;
        }
        h8 fx;
        #pragma unroll
        for (int jj = 0; jj < 8; ++jj) {
            const int k = quad * 8 + jj;
            float s = 0.0f;
            if (k < IN_F) {
                #pragma unroll 1
                for (int m = 0; m < D_FC; ++m)
                    s = fmaf(W_ih[n * D_FC + m], W0[m * IN_F + k], s);
            }
            fx[jj] = (_Float16)s;
        }
        Bx[q] = fx;
        // fused bias (b_ih + b_hh + W_ih@b0), pre-scaled for exp2-arg folding
        float bf = b_ih[n] + b_hh[n];
        #pragma unroll 1
        for (int m = 0; m < D_FC; ++m)
            bf = fmaf(W_ih[n * D_FC + m], b0[m], bf);
        bsc[q] = (q == 2) ? TWOLOG2E * bf : -LOG2E * bf;
    }

    // ---- x staging: threads 0..39 each own (batch fb, feature fi) ----
    const bool xact = (tid < MB * IN_F);
    const int  fb   = tid / IN_F;           // 0..7 (when xact)
    const int  fi   = tid - fb * IN_F;      // 0..4
    const int  frow = mrow(fb & 7);
    const float* xptr = x + (size_t)(bblk + (fb & 7)) * T_STEPS * IN_F + fi;

    // ---- zero both buffers (x pad + garbage rows must stay 0) ----
    {
        unsigned* p = (unsigned*)&H[0][0][0];
        #pragma unroll
        for (int i = 0; i < 7; ++i) {       // 2*16*104/2 = 1664 dwords
            const int idx = tid + 256 * i;
            if (idx < 1664) p[idx] = 0u;
        }
    }
    __syncthreads();
    // seed x(0) into buf 0; prefetch x(1)
    if (xact) H[0][frow][fi] = (_Float16)xptr[0];
    float xr = xact ? xptr[IN_F] : 0.0f;

    // cell state: lane owns (batch quad*2+r, j=w*16+col), r=0,1
    float c_st[2] = {0.0f, 0.0f};
    const f4 zero4 = {0.0f, 0.0f, 0.0f, 0.0f};

    __syncthreads();

    for (int t = 0; t < T_STEPS; ++t) {
        const int rp = t & 1, wp = rp ^ 1;

        // post-barrier reads first: h-chunks (on-chain), then x-chunk
        const h8 A1 = *(const h8*)&H[rp][col][HOFF + quad * 8];
        const h8 A2 = *(const h8*)&H[rp][col][HOFF + 32 + quad * 8];
        const h8 A0 = *(const h8*)&H[rp][col][quad * 8];

        // independent accumulators: chain depth = ONE mfma
        f4 u[4], v[4], xa[4];
        #pragma unroll
        for (int q = 0; q < 4; ++q) u[q]  = __builtin_amdgcn_mfma_f32_16x16x32_f16(A1, Bh[q][0], zero4, 0, 0, 0);
        #pragma unroll
        for (int q = 0; q < 4; ++q) v[q]  = __builtin_amdgcn_mfma_f32_16x16x32_f16(A2, Bh[q][1], zero4, 0, 0, 0);
        #pragma unroll
        for (int q = 0; q < 4; ++q) xa[q] = __builtin_amdgcn_mfma_f32_16x16x32_f16(A0, Bx[q],    zero4, 0, 0, 0);

        // elementwise LSTM: 2 cells per lane (rows quad*4 + {0,1})
        #pragma unroll
        for (int r = 0; r < 2; ++r) {
            const float gi = u[0][r] + v[0][r] + xa[0][r];
            const float gf = u[1][r] + v[1][r] + xa[1][r];
            const float gg = u[2][r] + v[2][r] + xa[2][r];
            const float go = u[3][r] + v[3][r] + xa[3][r];
            const float ii = frcp(1.0f + fexp2(fmaf(-LOG2E,   gi, bsc[0])));
            const float ff = frcp(1.0f + fexp2(fmaf(-LOG2E,   gf, bsc[1])));
            const float g_ = fmaf(-2.0f, frcp(1.0f + fexp2(fmaf(TWOLOG2E, gg, bsc[2]))), 1.0f);
            const float oo = frcp(1.0f + fexp2(fmaf(-LOG2E,   go, bsc[3])));
            c_st[r] = fmaf(ff, c_st[r], ii * g_);
            const float th = fmaf(-2.0f, frcp(1.0f + fexp2(TWOLOG2E * c_st[r])), 1.0f);
            H[wp][quad * 4 + r][HOFF + w * 16 + col] = (_Float16)(oo * th);
        }

        // off-chain: stage x(t+1), prefetch x(t+2)
        if (xact) H[wp][frow][fi] = (_Float16)xr;
        const int tn = (t + 2 < T_STEPS) ? (t + 2) : (T_STEPS - 1);
        if (xact) xr = xptr[(size_t)tn * IN_F];

        __syncthreads();   // single barrier: buf[wp] writes visible for next step
    }

    // ---- output head: h_last in buf 0 (T even); batch b at row mrow(b) ----
    if (tid < MB) {
        const int hr = mrow(tid);
        float a = bo[0];
        #pragma unroll 8
        for (int j = 0; j < D_H; ++j)
            a = fmaf((float)H[0][hr][HOFF + j], Wo[j], a);
        out[bblk + tid] = a;
    }
}

extern "C" void kernel_launch(void* const* d_in, const int* in_sizes, int n_in,
                              void* d_out, int out_size, void* d_ws, size_t ws_size,
                              hipStream_t stream) {
    const float* x    = (const float*)d_in[0];
    const float* W0   = (const float*)d_in[1];
    const float* b0   = (const float*)d_in[2];
    const float* W_ih = (const float*)d_in[3];
    const float* W_hh = (const float*)d_in[4];
    const float* b_ih = (const float*)d_in[5];
    const float* b_hh = (const float*)d_in[6];
    const float* Wo   = (const float*)d_in[7];
    const float* bo   = (const float*)d_in[8];
    float* out = (float*)d_out;

    hipLaunchKernelGGL(lstm_mfma, dim3(B_TOT / MB), dim3(256), 0, stream,
                       x, W0, b0, W_ih, W_hh, b_ih, b_hh, Wo, bo, out);
}